// Round 11
// baseline (400.577 us; speedup 1.0000x reference)
//
#include <hip/hip_runtime.h>
#include <math.h>

// ---------------------------------------------------------------------------
// CAGPool layer, MI355X. Outputs concatenated flat as float32 values:
//   [0]      : x_out          [B*k, D]
//   [o1]     : edge_index_new [2, E]  (ids as floats, -1 for dropped)
//   [o2]     : batch_out      [B*k]
//   [o3]     : perm           [B*k]
//   [o4]     : valid          [E]   (0.0 / 1.0)
//
// Ordering must match jax.lax.top_k exactly. Scores in float64, bit-identical
// per-row summation structure across all passing rounds.
//
// Fast path (R10 counters: srg at 37% occupancy / 1.9 TB/s, edge kernel
// serialized behind it at full BW): ONE kernel, grid = 2B blocks.
//   blocks 0..B-1   : score -> rank -> (flags[b] release) -> gather
//   blocks B..2B-1  : spin-acquire flags[g], then remap graph g's edges.
// 2 resident 1024-thread blocks/CU (launch_bounds(1024,8), 12KB LDS) ->
// edge phase overlaps score/rank/gather and fills idle wave slots.
// Producers are blocks 0..B-1 (dispatched first); co-residency of all 2B
// blocks is resource-guaranteed, so the spin cannot deadlock.
// ---------------------------------------------------------------------------

typedef float  nfloat4 __attribute__((ext_vector_type(4)));
typedef int    nint4   __attribute__((ext_vector_type(4)));

__device__ __forceinline__ void nt_store4(float4* p, float4 v) {
    nfloat4 nv = { v.x, v.y, v.z, v.w };
    __builtin_nontemporal_store(nv, reinterpret_cast<nfloat4*>(p));
}
__device__ __forceinline__ int4 nt_load4(const int4* p) {
    nint4 nv = __builtin_nontemporal_load(reinterpret_cast<const nint4*>(p));
    int4 r; r.x = nv.x; r.y = nv.y; r.z = nv.z; r.w = nv.w;
    return r;
}

__global__ __launch_bounds__(1024, 8)
void fused_kernel(const float4* __restrict__ x4,
                  const float4* __restrict__ pool4,
                  const int4* __restrict__ ei_src4,
                  const int4* __restrict__ ei_dst4,
                  int* __restrict__ nodemap,
                  int* __restrict__ flags,
                  float4* __restrict__ out0,
                  float4* __restrict__ out_row,
                  float4* __restrict__ out_col,
                  float4* __restrict__ out_valid,
                  float* __restrict__ out_batch,
                  float* __restrict__ out_perm,
                  int B, int n, int k, int Eg4) {
    __shared__ double s[1024];          // scores | (edge path: int nodemap cache)
    __shared__ int    perm_l[512];
    __shared__ float  gate_l[512];

    const int bid = blockIdx.x;
    const int t = threadIdx.x;

    if (bid < B) {
        // ================= producer: score + rank + gather =================
        const int b = bid;
        const int w = t >> 6, l = t & 63;
        const int nw = 16;                       // 1024 threads = 16 waves

        // ---- phase 1: scores (bit-identical structure) ----
        float4 pv = pool4[(size_t)b * 64 + l];   // D=256: one float4 per lane
        double px = pv.x, py = pv.y, pz = pv.z, pw = pv.w;
        double nn = px * px + py * py + pz * pz + pw * pw;
        for (int off = 32; off > 0; off >>= 1) nn += __shfl_xor(nn, off, 64);
        double inv = 1.0 / sqrt(nn);

        const int npw = n / nw;                  // nodes per wave (mult of 4)
        const float4* xg = x4 + ((size_t)b * n + (size_t)w * npw) * 64;

        float4 va = xg[l], vb = xg[64 + l], vc = xg[128 + l], vd = xg[192 + l];
        for (int i = 0; i < npw; i += 4) {
            float4 na, nb, nc, nd;
            bool more = (i + 4 < npw);
            if (more) {
                const float4* xn = xg + (size_t)(i + 4) * 64;
                na = xn[l]; nb = xn[64 + l]; nc = xn[128 + l]; nd = xn[192 + l];
            }
            double da = (double)va.x * px + (double)va.y * py
                      + (double)va.z * pz + (double)va.w * pw;
            double db = (double)vb.x * px + (double)vb.y * py
                      + (double)vb.z * pz + (double)vb.w * pw;
            double dc = (double)vc.x * px + (double)vc.y * py
                      + (double)vc.z * pz + (double)vc.w * pw;
            double dd = (double)vd.x * px + (double)vd.y * py
                      + (double)vd.z * pz + (double)vd.w * pw;
            for (int off = 32; off > 0; off >>= 1) {
                da += __shfl_xor(da, off, 64);
                db += __shfl_xor(db, off, 64);
                dc += __shfl_xor(dc, off, 64);
                dd += __shfl_xor(dd, off, 64);
            }
            if (l == 0) {
                int base = w * npw + i;
                s[base]     = da * inv;
                s[base + 1] = db * inv;
                s[base + 2] = dc * inv;
                s[base + 3] = dd * inv;
            }
            if (more) { va = na; vb = nb; vc = nc; vd = nd; }
        }
        __syncthreads();

        // ---- phase 2: exact top-k rank ----
        if (t < n) {
            double st = s[t];
            int rank = 0;
#pragma unroll 8
            for (int j = 0; j < n; ++j) {
                double sj = s[j];
                rank += (int)((sj > st) || (sj == st && j < t));
            }
            if (rank < k) {
                int p = b * k + rank;
                nodemap[b * n + t] = p;
                perm_l[rank] = t;
                gate_l[rank] = (float)(1.0 / (1.0 + exp(-st)));
                out_batch[p] = (float)b;
                out_perm[p]  = (float)(b * n + t);
            } else {
                nodemap[b * n + t] = -1;
            }
        }
        __threadfence();                          // make nodemap device-visible
        __syncthreads();                          // all threads fenced
        if (t == 0)
            __hip_atomic_store(&flags[b], 1, __ATOMIC_RELEASE,
                               __HIP_MEMORY_SCOPE_AGENT);

        // ---- phase 3: gather x_out (x rows still cache-hot) ----
        {
            const size_t xbase = (size_t)b * n * 64;
            const size_t obase = (size_t)b * k * 64;
            const int rpw = k / 16;               // rows per wave (mult of 4)
            const int rbase = w * rpw;
            for (int i = 0; i < rpw; i += 4) {
                int r0 = rbase + i;
                int g0 = perm_l[r0],     g1 = perm_l[r0 + 1];
                int g2 = perm_l[r0 + 2], g3 = perm_l[r0 + 3];
                float f0 = gate_l[r0],     f1 = gate_l[r0 + 1];
                float f2 = gate_l[r0 + 2], f3 = gate_l[r0 + 3];
                float4 v0 = x4[xbase + (size_t)g0 * 64 + l];
                float4 v1 = x4[xbase + (size_t)g1 * 64 + l];
                float4 v2 = x4[xbase + (size_t)g2 * 64 + l];
                float4 v3 = x4[xbase + (size_t)g3 * 64 + l];
                v0.x *= f0; v0.y *= f0; v0.z *= f0; v0.w *= f0;
                v1.x *= f1; v1.y *= f1; v1.z *= f1; v1.w *= f1;
                v2.x *= f2; v2.y *= f2; v2.z *= f2; v2.w *= f2;
                v3.x *= f3; v3.y *= f3; v3.z *= f3; v3.w *= f3;
                nt_store4(&out0[obase + (size_t)(r0    ) * 64 + l], v0);
                nt_store4(&out0[obase + (size_t)(r0 + 1) * 64 + l], v1);
                nt_store4(&out0[obase + (size_t)(r0 + 2) * 64 + l], v2);
                nt_store4(&out0[obase + (size_t)(r0 + 3) * 64 + l], v3);
            }
        }
    } else {
        // ================= consumer: edge remap for graph g =================
        const int g = bid - B;
        while (__hip_atomic_load(&flags[g], __ATOMIC_ACQUIRE,
                                 __HIP_MEMORY_SCOPE_AGENT) == 0)
            __builtin_amdgcn_s_sleep(8);

        int* smap = (int*)s;                     // reuse LDS as int cache
        const int nbase = g * n;
        for (int i = t; i < n; i += 1024)
            smap[i] = nodemap[nbase + i];
        __syncthreads();

        const long e4base = (long)g * Eg4;
        for (int i = t; i < Eg4; i += 1024) {
            long e = e4base + i;
            int4 sv = nt_load4(&ei_src4[e]);
            int4 dv = nt_load4(&ei_dst4[e]);
            int r0 = smap[sv.x - nbase], r1 = smap[sv.y - nbase];
            int r2 = smap[sv.z - nbase], r3 = smap[sv.w - nbase];
            int c0 = smap[dv.x - nbase], c1 = smap[dv.y - nbase];
            int c2 = smap[dv.z - nbase], c3 = smap[dv.w - nbase];
            bool v0 = (r0 >= 0) & (c0 >= 0);
            bool v1 = (r1 >= 0) & (c1 >= 0);
            bool v2 = (r2 >= 0) & (c2 >= 0);
            bool v3 = (r3 >= 0) & (c3 >= 0);
            float4 rv = { v0 ? (float)r0 : -1.0f, v1 ? (float)r1 : -1.0f,
                          v2 ? (float)r2 : -1.0f, v3 ? (float)r3 : -1.0f };
            float4 cv = { v0 ? (float)c0 : -1.0f, v1 ? (float)c1 : -1.0f,
                          v2 ? (float)c2 : -1.0f, v3 ? (float)c3 : -1.0f };
            float4 vv = { v0 ? 1.0f : 0.0f, v1 ? 1.0f : 0.0f,
                          v2 ? 1.0f : 0.0f, v3 ? 1.0f : 0.0f };
            nt_store4(&out_row[e], rv);
            nt_store4(&out_col[e], cv);
            nt_store4(&out_valid[e], vv);
        }
    }
}

// ======================= fallback path (general sizes) ======================
__global__ void norm_kernel(const float* __restrict__ pool,
                            double* __restrict__ inv_norm, int D) {
    int b = blockIdx.x;
    int l = threadIdx.x;
    double acc = 0.0;
    for (int j = l; j < D; j += 64) {
        double v = (double)pool[(size_t)b * D + j];
        acc += v * v;
    }
    for (int off = 32; off > 0; off >>= 1) acc += __shfl_down(acc, off, 64);
    if (l == 0) inv_norm[b] = 1.0 / sqrt(acc);
}

__global__ void score_kernel(const float* __restrict__ x,
                             const float* __restrict__ pool,
                             const double* __restrict__ inv_norm,
                             double* __restrict__ scores,
                             int D, int n) {
    int node = blockIdx.x * 4 + (threadIdx.x >> 6);
    int l = threadIdx.x & 63;
    int b = node / n;
    const float* xr = x + (size_t)node * D;
    const float* pr = pool + (size_t)b * D;
    double acc = 0.0;
    for (int j = l; j < D; j += 64)
        acc += (double)xr[j] * (double)pr[j];
    for (int off = 32; off > 0; off >>= 1) acc += __shfl_down(acc, off, 64);
    if (l == 0) scores[node] = acc * inv_norm[b];
}

__global__ void rank_kernel(const double* __restrict__ scores,
                            int* __restrict__ nodemap,
                            int* __restrict__ perm_int,
                            float* __restrict__ out,
                            long off_batch, long off_perm,
                            int n, int k) {
    extern __shared__ double sdyn[];
    int b = blockIdx.x;
    int t = threadIdx.x;
    int gid = b * n + t;
    double st = scores[gid];
    sdyn[t] = st;
    __syncthreads();
    int rank = 0;
    for (int j = 0; j < n; ++j) {
        double sj = sdyn[j];
        rank += (int)((sj > st) || (sj == st && j < t));
    }
    if (rank < k) {
        int p = b * k + rank;
        nodemap[gid] = p;
        perm_int[p] = gid;
        out[off_batch + p] = (float)b;
        out[off_perm + p]  = (float)gid;
    } else {
        nodemap[gid] = -1;
    }
}

__global__ void gather_kernel(const float* __restrict__ x,
                              const double* __restrict__ scores,
                              const int* __restrict__ perm_int,
                              float* __restrict__ out0, int D) {
    int p = blockIdx.x;
    int l = threadIdx.x;
    int gid = perm_int[p];
    double sc = scores[gid];
    float g = (float)(1.0 / (1.0 + exp(-sc)));
    const float* xr = x + (size_t)gid * D;
    float* orow = out0 + (size_t)p * D;
    for (int j = l; j < D; j += 64) orow[j] = xr[j] * g;
}

__global__ void edge_kernel(const int* __restrict__ ei,
                            const int* __restrict__ nodemap,
                            float* __restrict__ out,
                            long off_e, long off_valid, long E) {
    long e = (long)blockIdx.x * blockDim.x + threadIdx.x;
    if (e >= E) return;
    int r = nodemap[ei[e]];
    int c = nodemap[ei[E + e]];
    bool valid = (r >= 0) && (c >= 0);
    out[off_e + e]     = valid ? (float)r : -1.0f;
    out[off_e + E + e] = valid ? (float)c : -1.0f;
    out[off_valid + e] = valid ? 1.0f : 0.0f;
}

// ============================================================================
extern "C" void kernel_launch(void* const* d_in, const int* in_sizes, int n_in,
                              void* d_out, int out_size, void* d_ws, size_t ws_size,
                              hipStream_t stream) {
    const float* x    = (const float*)d_in[0];
    const int*   ei   = (const int*)d_in[1];
    const float* pool = (const float*)d_in[3];

    const int B = in_sizes[4];
    const int D = in_sizes[3] / B;
    const long N = (long)in_sizes[0] / D;
    const long E = (long)in_sizes[1] / 2;
    const int n = (int)(N / B);
    const int k = (n + 1) / 2;            // ceil(0.5 * n)
    const long Eg = E / B;                // edges per graph

    // workspace layout
    char* ws = (char*)d_ws;
    double* scores   = (double*)ws;                 ws += (size_t)N * 8;
    double* inv_norm = (double*)ws;                 ws += (size_t)B * 8;
    int*    nodemap  = (int*)ws;                    ws += (size_t)N * 4;
    int*    flags    = (int*)ws;                    ws += (size_t)B * 4;
    int*    perm_int = (int*)ws;

    float* out = (float*)d_out;
    const long o0 = 0;                       // x_out [B*k, D]
    const long o1 = o0 + (long)B * k * D;    // edge_index_new [2, E]
    const long o2 = o1 + 2 * E;              // batch_out [B*k]
    const long o3 = o2 + (long)B * k;        // perm [B*k]
    const long o4 = o3 + (long)B * k;        // valid [E]

    bool fast_ok = (D == 256) && (n % 64 == 0) && (n <= 1024) && (k % 64 == 0) &&
                   (B <= 256) && (Eg % 4 == 0) && (E % 4 == 0) &&
                   (o1 % 4 == 0) && ((o1 + E) % 4 == 0) && (o4 % 4 == 0);

    if (fast_ok) {
        hipMemsetAsync(flags, 0, (size_t)B * 4, stream);
        fused_kernel<<<2 * B, 1024, 0, stream>>>(
            (const float4*)x, (const float4*)pool,
            (const int4*)ei, (const int4*)(ei + E),
            nodemap, flags,
            (float4*)(out + o0), (float4*)(out + o1),
            (float4*)(out + o1 + E), (float4*)(out + o4),
            out + o2, out + o3,
            B, n, k, (int)(Eg / 4));
    } else {
        norm_kernel<<<B, 64, 0, stream>>>(pool, inv_norm, D);
        score_kernel<<<(int)(N / 4), 256, 0, stream>>>(
            x, pool, inv_norm, scores, D, n);
        rank_kernel<<<B, n, (size_t)n * sizeof(double), stream>>>(
            scores, nodemap, perm_int, out, o2, o3, n, k);
        gather_kernel<<<(int)((long)B * k), 64, 0, stream>>>(
            x, scores, perm_int, out + o0, D);
        edge_kernel<<<(int)((E + 255) / 256), 256, 0, stream>>>(
            ei, nodemap, out, o1, o4, E);
    }
}

// Round 12
// 81.898 us; speedup vs baseline: 4.8911x; 4.8911x over previous
//
#include <hip/hip_runtime.h>
#include <math.h>

// ---------------------------------------------------------------------------
// CAGPool layer, MI355X. Outputs concatenated flat as float32 values:
//   [0]      : x_out          [B*k, D]
//   [o1]     : edge_index_new [2, E]  (ids as floats, -1 for dropped)
//   [o2]     : batch_out      [B*k]
//   [o3]     : perm           [B*k]
//   [o4]     : valid          [E]   (0.0 / 1.0)
//
// Ordering must match jax.lax.top_k exactly. Scores in float64; per-row
// summation structure (per-lane float4 fma order + __shfl_xor butterfly)
// IDENTICAL to all passing rounds.
//
// R11 lesson: spin-wait producer/consumer in one grid = 5x regression (256K
// spinning threads starve the memory system). Reverted to R10's 2-kernel
// structure; this round raises MLP instead:
//   K1 srg  : per-graph block. Score = 8 rows/iter + depth-1 prefetch
//             (16 rows in flight/wave). launch_bounds(1024,4) -> <=128 VGPR.
//   K2 edge : 4096 edges/block, 8 int4 loads in flight before LDS staging.
// ---------------------------------------------------------------------------

typedef float  nfloat4 __attribute__((ext_vector_type(4)));
typedef int    nint4   __attribute__((ext_vector_type(4)));

__device__ __forceinline__ void nt_store4(float4* p, float4 v) {
    nfloat4 nv = { v.x, v.y, v.z, v.w };
    __builtin_nontemporal_store(nv, reinterpret_cast<nfloat4*>(p));
}
__device__ __forceinline__ int4 nt_load4(const int4* p) {
    nint4 nv = __builtin_nontemporal_load(reinterpret_cast<const nint4*>(p));
    int4 r; r.x = nv.x; r.y = nv.y; r.z = nv.z; r.w = nv.w;
    return r;
}

__device__ __forceinline__ double dot4(float4 v, double px, double py,
                                       double pz, double pw) {
    return (double)v.x * px + (double)v.y * py
         + (double)v.z * pz + (double)v.w * pw;
}

// --- K1: score + rank + gather, one 1024-thread block per graph -------------
__global__ __launch_bounds__(1024, 4)
void srg_kernel(const float4* __restrict__ x4,
                const float4* __restrict__ pool4,
                int* __restrict__ nodemap,
                float4* __restrict__ out0,
                float* __restrict__ out_batch,
                float* __restrict__ out_perm,
                int n, int k) {
    __shared__ double s[1024];
    __shared__ int    perm_l[512];
    __shared__ float  gate_l[512];

    const int b = blockIdx.x;
    const int t = threadIdx.x;
    const int w = t >> 6, l = t & 63;

    // ---- phase 1: scores (8 rows/iter, depth-1 prefetch) -------------------
    float4 pv = pool4[(size_t)b * 64 + l];      // D=256: one float4 per lane
    double px = pv.x, py = pv.y, pz = pv.z, pw = pv.w;
    double nn = px * px + py * py + pz * pz + pw * pw;
    for (int off = 32; off > 0; off >>= 1) nn += __shfl_xor(nn, off, 64);
    double inv = 1.0 / sqrt(nn);

    const int npw = n >> 4;                     // nodes per wave (mult of 8)
    const float4* xg = x4 + ((size_t)b * n + (size_t)w * npw) * 64;

    float4 c0 = xg[l],           c1 = xg[64 + l],  c2 = xg[128 + l],
           c3 = xg[192 + l],     c4 = xg[256 + l], c5 = xg[320 + l],
           c6 = xg[384 + l],     c7 = xg[448 + l];
    for (int i = 0; i < npw; i += 8) {
        float4 n0, n1, n2, n3, n4, n5, n6, n7;
        bool more = (i + 8 < npw);
        if (more) {                              // prefetch next 8 rows
            const float4* xn = xg + (size_t)(i + 8) * 64;
            n0 = xn[l];       n1 = xn[64 + l];  n2 = xn[128 + l];
            n3 = xn[192 + l]; n4 = xn[256 + l]; n5 = xn[320 + l];
            n6 = xn[384 + l]; n7 = xn[448 + l];
        }
        double d0 = dot4(c0, px, py, pz, pw);
        double d1 = dot4(c1, px, py, pz, pw);
        double d2 = dot4(c2, px, py, pz, pw);
        double d3 = dot4(c3, px, py, pz, pw);
        double d4 = dot4(c4, px, py, pz, pw);
        double d5 = dot4(c5, px, py, pz, pw);
        double d6 = dot4(c6, px, py, pz, pw);
        double d7 = dot4(c7, px, py, pz, pw);
        for (int off = 32; off > 0; off >>= 1) { // 8 independent chains
            d0 += __shfl_xor(d0, off, 64);
            d1 += __shfl_xor(d1, off, 64);
            d2 += __shfl_xor(d2, off, 64);
            d3 += __shfl_xor(d3, off, 64);
            d4 += __shfl_xor(d4, off, 64);
            d5 += __shfl_xor(d5, off, 64);
            d6 += __shfl_xor(d6, off, 64);
            d7 += __shfl_xor(d7, off, 64);
        }
        if (l == 0) {
            int base = w * npw + i;
            s[base]     = d0 * inv;
            s[base + 1] = d1 * inv;
            s[base + 2] = d2 * inv;
            s[base + 3] = d3 * inv;
            s[base + 4] = d4 * inv;
            s[base + 5] = d5 * inv;
            s[base + 6] = d6 * inv;
            s[base + 7] = d7 * inv;
        }
        if (more) {
            c0 = n0; c1 = n1; c2 = n2; c3 = n3;
            c4 = n4; c5 = n5; c6 = n6; c7 = n7;
        }
    }
    __syncthreads();

    // ---- phase 2: exact top-k rank -----------------------------------------
    if (t < n) {
        double st = s[t];
        int rank = 0;
#pragma unroll 8
        for (int j = 0; j < n; ++j) {
            double sj = s[j];
            rank += (int)((sj > st) || (sj == st && j < t));
        }
        if (rank < k) {
            int p = b * k + rank;
            nodemap[b * n + t] = p;
            perm_l[rank] = t;
            gate_l[rank] = (float)(1.0 / (1.0 + exp(-st)));
            out_batch[p] = (float)b;
            out_perm[p]  = (float)(b * n + t);
        } else {
            nodemap[b * n + t] = -1;
        }
    }
    __syncthreads();

    // ---- phase 3: gather x_out (x rows L2/L3-hot) --------------------------
    {
        const size_t xbase = (size_t)b * n * 64;
        const size_t obase = (size_t)b * k * 64;
        const int rpw = k >> 4;                  // rows per wave (mult of 4)
        const int rbase = w * rpw;
        for (int i = 0; i < rpw; i += 4) {
            int r0 = rbase + i;
            int g0 = perm_l[r0],     g1 = perm_l[r0 + 1];
            int g2 = perm_l[r0 + 2], g3 = perm_l[r0 + 3];
            float f0 = gate_l[r0],     f1 = gate_l[r0 + 1];
            float f2 = gate_l[r0 + 2], f3 = gate_l[r0 + 3];
            float4 v0 = x4[xbase + (size_t)g0 * 64 + l];
            float4 v1 = x4[xbase + (size_t)g1 * 64 + l];
            float4 v2 = x4[xbase + (size_t)g2 * 64 + l];
            float4 v3 = x4[xbase + (size_t)g3 * 64 + l];
            v0.x *= f0; v0.y *= f0; v0.z *= f0; v0.w *= f0;
            v1.x *= f1; v1.y *= f1; v1.z *= f1; v1.w *= f1;
            v2.x *= f2; v2.y *= f2; v2.z *= f2; v2.w *= f2;
            v3.x *= f3; v3.y *= f3; v3.z *= f3; v3.w *= f3;
            nt_store4(&out0[obase + (size_t)(r0    ) * 64 + l], v0);
            nt_store4(&out0[obase + (size_t)(r0 + 1) * 64 + l], v1);
            nt_store4(&out0[obase + (size_t)(r0 + 2) * 64 + l], v2);
            nt_store4(&out0[obase + (size_t)(r0 + 3) * 64 + l], v3);
        }
    }
}

// --- K2: edge remap + validity, 4096 edges/block, MLP=8 ---------------------
__global__ __launch_bounds__(256)
void edge_out_kernel(const int4* __restrict__ ei_src,
                     const int4* __restrict__ ei_dst,
                     const int* __restrict__ nodemap,
                     float4* __restrict__ out_row,
                     float4* __restrict__ out_col,
                     float4* __restrict__ out_valid,
                     long epg4, int n) {
    __shared__ int smem[1024];
    const long e4base = (long)blockIdx.x * 1024;  // int4 units -> 4096 edges
    const long g = e4base / epg4;
    const int base = (int)(g * (long)n);
    const int t = threadIdx.x;

    long e0 = e4base + t, e1 = e0 + 256, e2 = e0 + 512, e3 = e0 + 768;
    int4 s0 = nt_load4(&ei_src[e0]);
    int4 s1 = nt_load4(&ei_src[e1]);
    int4 s2 = nt_load4(&ei_src[e2]);
    int4 s3 = nt_load4(&ei_src[e3]);
    int4 d0 = nt_load4(&ei_dst[e0]);
    int4 d1 = nt_load4(&ei_dst[e1]);
    int4 d2 = nt_load4(&ei_dst[e2]);
    int4 d3 = nt_load4(&ei_dst[e3]);
    for (int i = t; i < n; i += 256)
        smem[i] = nodemap[base + i];
    __syncthreads();

#define EDGE_EMIT(sv, dv, e)                                                  \
    {                                                                         \
        int r0 = smem[sv.x - base], r1 = smem[sv.y - base];                   \
        int r2 = smem[sv.z - base], r3 = smem[sv.w - base];                   \
        int c0 = smem[dv.x - base], c1 = smem[dv.y - base];                   \
        int c2 = smem[dv.z - base], c3 = smem[dv.w - base];                   \
        bool v0 = (r0 >= 0) & (c0 >= 0);                                      \
        bool v1 = (r1 >= 0) & (c1 >= 0);                                      \
        bool v2 = (r2 >= 0) & (c2 >= 0);                                      \
        bool v3 = (r3 >= 0) & (c3 >= 0);                                      \
        float4 rv = { v0 ? (float)r0 : -1.0f, v1 ? (float)r1 : -1.0f,         \
                      v2 ? (float)r2 : -1.0f, v3 ? (float)r3 : -1.0f };       \
        float4 cv = { v0 ? (float)c0 : -1.0f, v1 ? (float)c1 : -1.0f,         \
                      v2 ? (float)c2 : -1.0f, v3 ? (float)c3 : -1.0f };       \
        float4 vv = { v0 ? 1.0f : 0.0f, v1 ? 1.0f : 0.0f,                     \
                      v2 ? 1.0f : 0.0f, v3 ? 1.0f : 0.0f };                   \
        nt_store4(&out_row[e], rv);                                           \
        nt_store4(&out_col[e], cv);                                           \
        nt_store4(&out_valid[e], vv);                                         \
    }

    EDGE_EMIT(s0, d0, e0)
    EDGE_EMIT(s1, d1, e1)
    EDGE_EMIT(s2, d2, e2)
    EDGE_EMIT(s3, d3, e3)
#undef EDGE_EMIT
}

// ======================= fallback path (general sizes) ======================
__global__ void norm_kernel(const float* __restrict__ pool,
                            double* __restrict__ inv_norm, int D) {
    int b = blockIdx.x;
    int l = threadIdx.x;
    double acc = 0.0;
    for (int j = l; j < D; j += 64) {
        double v = (double)pool[(size_t)b * D + j];
        acc += v * v;
    }
    for (int off = 32; off > 0; off >>= 1) acc += __shfl_down(acc, off, 64);
    if (l == 0) inv_norm[b] = 1.0 / sqrt(acc);
}

__global__ void score_kernel(const float* __restrict__ x,
                             const float* __restrict__ pool,
                             const double* __restrict__ inv_norm,
                             double* __restrict__ scores,
                             int D, int n) {
    int node = blockIdx.x * 4 + (threadIdx.x >> 6);
    int l = threadIdx.x & 63;
    int b = node / n;
    const float* xr = x + (size_t)node * D;
    const float* pr = pool + (size_t)b * D;
    double acc = 0.0;
    for (int j = l; j < D; j += 64)
        acc += (double)xr[j] * (double)pr[j];
    for (int off = 32; off > 0; off >>= 1) acc += __shfl_down(acc, off, 64);
    if (l == 0) scores[node] = acc * inv_norm[b];
}

__global__ void rank_kernel(const double* __restrict__ scores,
                            int* __restrict__ nodemap,
                            int* __restrict__ perm_int,
                            float* __restrict__ out,
                            long off_batch, long off_perm,
                            int n, int k) {
    extern __shared__ double sdyn[];
    int b = blockIdx.x;
    int t = threadIdx.x;
    int gid = b * n + t;
    double st = scores[gid];
    sdyn[t] = st;
    __syncthreads();
    int rank = 0;
    for (int j = 0; j < n; ++j) {
        double sj = sdyn[j];
        rank += (int)((sj > st) || (sj == st && j < t));
    }
    if (rank < k) {
        int p = b * k + rank;
        nodemap[gid] = p;
        perm_int[p] = gid;
        out[off_batch + p] = (float)b;
        out[off_perm + p]  = (float)gid;
    } else {
        nodemap[gid] = -1;
    }
}

__global__ void gather_kernel(const float* __restrict__ x,
                              const double* __restrict__ scores,
                              const int* __restrict__ perm_int,
                              float* __restrict__ out0, int D) {
    int p = blockIdx.x;
    int l = threadIdx.x;
    int gid = perm_int[p];
    double sc = scores[gid];
    float g = (float)(1.0 / (1.0 + exp(-sc)));
    const float* xr = x + (size_t)gid * D;
    float* orow = out0 + (size_t)p * D;
    for (int j = l; j < D; j += 64) orow[j] = xr[j] * g;
}

__global__ void edge_kernel(const int* __restrict__ ei,
                            const int* __restrict__ nodemap,
                            float* __restrict__ out,
                            long off_e, long off_valid, long E) {
    long e = (long)blockIdx.x * blockDim.x + threadIdx.x;
    if (e >= E) return;
    int r = nodemap[ei[e]];
    int c = nodemap[ei[E + e]];
    bool valid = (r >= 0) && (c >= 0);
    out[off_e + e]     = valid ? (float)r : -1.0f;
    out[off_e + E + e] = valid ? (float)c : -1.0f;
    out[off_valid + e] = valid ? 1.0f : 0.0f;
}

// ============================================================================
extern "C" void kernel_launch(void* const* d_in, const int* in_sizes, int n_in,
                              void* d_out, int out_size, void* d_ws, size_t ws_size,
                              hipStream_t stream) {
    const float* x    = (const float*)d_in[0];
    const int*   ei   = (const int*)d_in[1];
    const float* pool = (const float*)d_in[3];

    const int B = in_sizes[4];
    const int D = in_sizes[3] / B;
    const long N = (long)in_sizes[0] / D;
    const long E = (long)in_sizes[1] / 2;
    const int n = (int)(N / B);
    const int k = (n + 1) / 2;            // ceil(0.5 * n)
    const long Eg = E / B;                // edges per graph

    // workspace layout
    char* ws = (char*)d_ws;
    double* scores   = (double*)ws;                 ws += (size_t)N * 8;
    double* inv_norm = (double*)ws;                 ws += (size_t)B * 8;
    int*    nodemap  = (int*)ws;                    ws += (size_t)N * 4;
    int*    perm_int = (int*)ws;

    float* out = (float*)d_out;
    const long o0 = 0;                       // x_out [B*k, D]
    const long o1 = o0 + (long)B * k * D;    // edge_index_new [2, E]
    const long o2 = o1 + 2 * E;              // batch_out [B*k]
    const long o3 = o2 + (long)B * k;        // perm [B*k]
    const long o4 = o3 + (long)B * k;        // valid [E]

    bool fast_ok = (D == 256) && (n % 128 == 0) && (n <= 1024) &&
                   (k % 64 == 0) &&
                   (E % 4096 == 0) && (Eg % 4096 == 0) &&
                   (o1 % 4 == 0) && ((o1 + E) % 4 == 0) && (o4 % 4 == 0);

    if (fast_ok) {
        srg_kernel<<<B, 1024, 0, stream>>>(
            (const float4*)x, (const float4*)pool, nodemap,
            (float4*)(out + o0), out + o2, out + o3, n, k);
        edge_out_kernel<<<(int)(E / 4096), 256, 0, stream>>>(
            (const int4*)ei, (const int4*)(ei + E), nodemap,
            (float4*)(out + o1), (float4*)(out + o1 + E), (float4*)(out + o4),
            Eg / 4, n);
    } else {
        norm_kernel<<<B, 64, 0, stream>>>(pool, inv_norm, D);
        score_kernel<<<(int)(N / 4), 256, 0, stream>>>(
            x, pool, inv_norm, scores, D, n);
        rank_kernel<<<B, n, (size_t)n * sizeof(double), stream>>>(
            scores, nodemap, perm_int, out, o2, o3, n, k);
        gather_kernel<<<(int)((long)B * k), 64, 0, stream>>>(
            x, scores, perm_int, out + o0, D);
        edge_kernel<<<(int)((E + 255) / 256), 256, 0, stream>>>(
            ei, nodemap, out, o1, o4, E);
    }
}